// Round 1
// 8964.481 us; speedup vs baseline: 1.2266x; 1.2266x over previous
//
#include <hip/hip_runtime.h>
#include <stdint.h>

#define Tt 1024
#define Bt 128
#define Vt 256

typedef __attribute__((ext_vector_type(8))) short bf16x8;
typedef __attribute__((ext_vector_type(4))) float f32x4;

#define MFMA(a, b, c) __builtin_amdgcn_mfma_f32_16x16x32_bf16(a, b, c, 0, 0, 0)

__device__ __forceinline__ unsigned short f2bf(float f) {
    unsigned u = __builtin_bit_cast(unsigned, f);
    u += 0x7fffu + ((u >> 16) & 1u);
    return (unsigned short)(u >> 16);
}
// v_rcp_f32-based: avoids the precise-division sequence (~10 instr each).
// 1+e in [1,2] -> rcp approx error ~1e-7, far under the bf16 noise floor.
__device__ __forceinline__ float sigm(float x) {
    return __builtin_amdgcn_rcpf(1.f + __expf(-x));
}
__device__ __forceinline__ float tanh_f(float x) {
    float e = __expf(-2.f * fabsf(x));
    float t = (1.f - e) * __builtin_amdgcn_rcpf(1.f + e);
    return copysignf(t, x);
}

// agent-coherent 16B load (sc0 sc1 = bypass L1+L2, read at MALL). NO wait
// attached: caller batches 16-32 of these then does ONE vm_drain(). This is
// the core fix -- one MALL round-trip per batch instead of one per load.
template <int OFF>
__device__ __forceinline__ bf16x8 ldcc(const unsigned short* p) {
    bf16x8 d;
    asm volatile("global_load_dwordx4 %0, %1, off offset:%c2 sc0 sc1"
                 : "=v"(d)
                 : "v"(p), "i"(OFF));
    return d;
}
#define LDROW(dst, p)                                  \
    do {                                               \
        dst[0] = ldcc<0>(p);   dst[1] = ldcc<64>(p);   \
        dst[2] = ldcc<128>(p); dst[3] = ldcc<192>(p);  \
        dst[4] = ldcc<256>(p); dst[5] = ldcc<320>(p);  \
        dst[6] = ldcc<384>(p); dst[7] = ldcc<448>(p);  \
    } while (0)

__device__ __forceinline__ void vm_drain() {
    asm volatile("s_waitcnt vmcnt(0)" ::: "memory");
    __builtin_amdgcn_sched_barrier(0);  // rule #18: keep MFMAs below the wait
}

// 128 producer waves per layer (32 WGs x 4 waves) each publish a private
// monotonic step counter (pure store, no RMW -> no same-line atomic
// serialization). Consumer wave w needs only batch rows [32w,32w+32), i.e.
// only producer waves with the same w: poll 32 counters (16B stride, 8 cache
// lines) with one vector load.
__device__ __forceinline__ void wait_prog(unsigned* prog, int w, int target, int lane) {
    unsigned* p = prog + ((lane & 31) * 4 + w);
    for (;;) {
        unsigned v = __hip_atomic_load(p, __ATOMIC_RELAXED, __HIP_MEMORY_SCOPE_AGENT);
        if (__all((int)v >= target)) break;
        __builtin_amdgcn_s_sleep(2);
    }
    asm volatile("" ::: "memory");
}

// ---------------- x [B,T,V] fp32 -> xT [T,B,V] bf16 ----------------
__global__ __launch_bounds__(256) void cvt_kernel(const float* __restrict__ x,
                                                  unsigned short* __restrict__ xT) {
    unsigned g = blockIdx.x * 256u + threadIdx.x;
    unsigned base = g * 8u;
    unsigned r = base >> 8;  // r = t*128 + b
    unsigned v = base & 255u;
    unsigned t = r >> 7, b = r & 127u;
    const float4* src = (const float4*)(x + ((size_t)b * Tt + t) * Vt + v);
    float4 f0 = src[0], f1 = src[1];
    union { unsigned short s[8]; int4 q; } o;
    o.s[0] = f2bf(f0.x); o.s[1] = f2bf(f0.y); o.s[2] = f2bf(f0.z); o.s[3] = f2bf(f0.w);
    o.s[4] = f2bf(f1.x); o.s[5] = f2bf(f1.y); o.s[6] = f2bf(f1.z); o.s[7] = f2bf(f1.w);
    *(int4*)(xT + (size_t)r * Vt + v) = o.q;
}

// ---------------- persistent dataflow recurrence: 64 WGs ----------------
// wg 0..31 : layer 1, owns h-cols [8*sub, 8*sub+8); wg 32..63 : layer 2.
// Barrier-free steady loop: wave w of every WG forms an independent pipeline
// over batch rows [32w, 32w+32). h exchanged via MALL (sc0 sc1), readiness
// via per-wave progress counters.
__global__ __launch_bounds__(256) void rec_kernel(
    const float* __restrict__ Wih1, const float* __restrict__ Whh1,
    const float* __restrict__ bih1, const float* __restrict__ bhh1,
    const float* __restrict__ Wih2, const float* __restrict__ Whh2,
    const float* __restrict__ bih2, const float* __restrict__ bhh2,
    const unsigned short* __restrict__ xT,
    unsigned short* h1s, unsigned short* h2s,
    unsigned int* prog1, unsigned int* prog2) {
    const int wg = blockIdx.x;
    const int layer = wg >> 5;
    const int sub = wg & 31;
    const int hc0 = sub * 8;
    const float* Win = layer ? Wih2 : Wih1;
    const float* Whh = layer ? Whh2 : Whh1;
    const float* bi = layer ? bih2 : bih1;
    const float* bh = layer ? bhh2 : bhh1;

    __shared__ unsigned short sWin[32][264];  // +8 pad: conflict-light b128 reads
    __shared__ unsigned short sWhh[32][264];
    __shared__ unsigned short sH[128][8];     // per-wave-private rows [32w,32w+32)

    const int tid = threadIdx.x;
    {
        int m = tid >> 7;  // 0: Win, 1: Whh
        int lr = (tid >> 2) & 31;
        int seg = tid & 3;
        int grp = lr >> 3, local = lr & 7;
        int grow = 256 * grp + hc0 + local;
        const float* src = (m ? Whh : Win) + (size_t)grow * Vt + seg * 64;
        unsigned short* dst = m ? &sWhh[lr][seg * 64] : &sWin[lr][seg * 64];
        for (int k = 0; k < 64; k += 4) {
            float4 f = *(const float4*)(src + k);
            dst[k + 0] = f2bf(f.x); dst[k + 1] = f2bf(f.y);
            dst[k + 2] = f2bf(f.z); dst[k + 3] = f2bf(f.w);
        }
    }
    __syncthreads();  // only barrier in the kernel: weights staged

    const int lane = tid & 63;
    const int w = tid >> 6;  // wave 0..3 -> batch rows [32w, 32w+32)
    const int q = lane >> 4;
    const int ln = lane & 15;

    float biasv[2];
    for (int nb = 0; nb < 2; ++nb) {
        int grp = nb * 2 + (ln >> 3);
        int grow = 256 * grp + hc0 + (ln & 7);
        biasv[nb] = bi[grow] + bh[grow];
    }

    float cst[2][4];
#pragma unroll
    for (int rb = 0; rb < 2; ++rb)
#pragma unroll
        for (int r = 0; r < 4; ++r) cst[rb][r] = 0.f;

    const int rowoff0 = (32 * w + ln) * 256 + q * 8;
    const int rowoff1 = rowoff0 + 16 * 256;

    unsigned short* obbase = layer ? h2s : h1s;
    unsigned int* myprog = layer ? prog2 : prog1;

    // store-back lane mapping: lane l -> row 32w + (l>>1), 8B half (l&1)
    const int srow = 32 * w + (lane >> 1);
    const int shalf = lane & 1;
    unsigned short* obptr0 = obbase + (size_t)srow * 256 + hc0 + shalf * 4;

    for (int t = 0; t < Tt; ++t) {
        f32x4 acc[2][2];
#pragma unroll
        for (int rb = 0; rb < 2; ++rb)
#pragma unroll
            for (int nb = 0; nb < 2; ++nb)
                acc[rb][nb] = (f32x4){biasv[nb], biasv[nb], biasv[nb], biasv[nb]};

        if (layer == 0) {
            // x-proj GEMM first: entirely off the recurrence critical path
            const unsigned short* xp = xT + (size_t)t * (Bt * Vt);
            bf16x8 ax0[8], ax1[8];
#pragma unroll
            for (int kb = 0; kb < 8; ++kb) {
                ax0[kb] = *(const bf16x8*)(xp + rowoff0 + kb * 32);
                ax1[kb] = *(const bf16x8*)(xp + rowoff1 + kb * 32);
            }
#pragma unroll
            for (int kb = 0; kb < 8; ++kb) {
                bf16x8 b0 = *(const bf16x8*)&sWin[ln][kb * 32 + q * 8];
                bf16x8 b1 = *(const bf16x8*)&sWin[16 + ln][kb * 32 + q * 8];
                acc[0][0] = MFMA(ax0[kb], b0, acc[0][0]);
                acc[1][0] = MFMA(ax1[kb], b0, acc[1][0]);
                acc[0][1] = MFMA(ax0[kb], b1, acc[0][1]);
                acc[1][1] = MFMA(ax1[kb], b1, acc[1][1]);
            }
            if (t > 0) {
                wait_prog(prog1, w, t, lane);
                const unsigned short* hp = h1s + (size_t)(t - 1) * (Bt * Vt);
                bf16x8 ah0[8], ah1[8];
                LDROW(ah0, hp + rowoff0);
                LDROW(ah1, hp + rowoff1);
                vm_drain();
#pragma unroll
                for (int kb = 0; kb < 8; ++kb) {
                    bf16x8 b0 = *(const bf16x8*)&sWhh[ln][kb * 32 + q * 8];
                    bf16x8 b1 = *(const bf16x8*)&sWhh[16 + ln][kb * 32 + q * 8];
                    acc[0][0] = MFMA(ah0[kb], b0, acc[0][0]);
                    acc[1][0] = MFMA(ah1[kb], b0, acc[1][0]);
                    acc[0][1] = MFMA(ah0[kb], b1, acc[0][1]);
                    acc[1][1] = MFMA(ah1[kb], b1, acc[1][1]);
                }
            }
        } else {
            // own recurrence first (its flag is a full step older -> usually
            // ready); recurrent GEMM then hides under the wait for layer 1.
            if (t > 0) {
                wait_prog(prog2, w, t, lane);
                const unsigned short* hp = h2s + (size_t)(t - 1) * (Bt * Vt);
                bf16x8 ah0[8], ah1[8];
                LDROW(ah0, hp + rowoff0);
                LDROW(ah1, hp + rowoff1);
                vm_drain();
#pragma unroll
                for (int kb = 0; kb < 8; ++kb) {
                    bf16x8 b0 = *(const bf16x8*)&sWhh[ln][kb * 32 + q * 8];
                    bf16x8 b1 = *(const bf16x8*)&sWhh[16 + ln][kb * 32 + q * 8];
                    acc[0][0] = MFMA(ah0[kb], b0, acc[0][0]);
                    acc[1][0] = MFMA(ah1[kb], b0, acc[1][0]);
                    acc[0][1] = MFMA(ah0[kb], b1, acc[0][1]);
                    acc[1][1] = MFMA(ah1[kb], b1, acc[1][1]);
                }
            }
            wait_prog(prog1, w, t + 1, lane);
            const unsigned short* hp1 = h1s + (size_t)t * (Bt * Vt);
            bf16x8 ai0[8], ai1[8];
            LDROW(ai0, hp1 + rowoff0);
            LDROW(ai1, hp1 + rowoff1);
            vm_drain();
#pragma unroll
            for (int kb = 0; kb < 8; ++kb) {
                bf16x8 b0 = *(const bf16x8*)&sWin[ln][kb * 32 + q * 8];
                bf16x8 b1 = *(const bf16x8*)&sWin[16 + ln][kb * 32 + q * 8];
                acc[0][0] = MFMA(ai0[kb], b0, acc[0][0]);
                acc[1][0] = MFMA(ai1[kb], b0, acc[1][0]);
                acc[0][1] = MFMA(ai0[kb], b1, acc[0][1]);
                acc[1][1] = MFMA(ai1[kb], b1, acc[1][1]);
            }
        }

        // elementwise LSTM cell; lane ln holds (i|f) in acc[.][0], (g|o) in acc[.][1]
#pragma unroll
        for (int rb = 0; rb < 2; ++rb) {
#pragma unroll
            for (int r = 0; r < 4; ++r) {
                float a0 = acc[rb][0][r], a1 = acc[rb][1][r];
                float b0 = __shfl_xor(a0, 8);
                float b1 = __shfl_xor(a1, 8);
                float iv, fv, gv, ov;
                if (ln < 8) { iv = a0; fv = b0; gv = a1; ov = b1; }
                else        { iv = b0; fv = a0; gv = b1; ov = a1; }
                float ii = sigm(iv), ff = sigm(fv), gg = tanh_f(gv), oo = sigm(ov);
                float cc = ff * cst[rb][r] + ii * gg;
                cst[rb][r] = cc;
                float hh = oo * tanh_f(cc);
                if (ln < 8) sH[32 * w + rb * 16 + q * 4 + r][ln] = f2bf(hh);
            }
        }
        // wave-local LDS transpose (rows [32w,32w+32) private to this wave):
        // cross-lane within a wave needs only lgkmcnt(0), no barrier.
        asm volatile("s_waitcnt lgkmcnt(0)" ::: "memory");
        __builtin_amdgcn_sched_barrier(0);
        unsigned long long hv = *(const unsigned long long*)&sH[srow][shalf * 4];
        __hip_atomic_store((unsigned long long*)(obptr0 + (size_t)t * (Bt * Vt)), hv,
                           __ATOMIC_RELAXED, __HIP_MEMORY_SCOPE_AGENT);
        asm volatile("s_waitcnt vmcnt(0)" ::: "memory");  // h acked at MALL
        if (lane == 0)
            __hip_atomic_store(&myprog[sub * 4 + w], (unsigned)(t + 1),
                               __ATOMIC_RELAXED, __HIP_MEMORY_SCOPE_AGENT);
    }
}

// ---------------- out[b,t,:] = h2s[t,b,:] @ w_n^T + fc_b ----------------
__global__ __launch_bounds__(256) void fc_kernel(const unsigned short* __restrict__ h2s,
                                                 const float* __restrict__ fcw,
                                                 const float* __restrict__ fcb,
                                                 float* __restrict__ out) {
    const int bid = blockIdx.x;
    const int rb = bid >> 2;  // t
    const int c0 = (bid & 3) * 64;
    __shared__ unsigned short sW[64][264];
    __shared__ float sInv[64];
    const int tid = threadIdx.x;
    if (tid < 64) {
        const float* wr = fcw + (size_t)(c0 + tid) * 256;
        float s = 0.f;
        for (int k = 0; k < 256; k += 4) {
            float4 f = *(const float4*)(wr + k);
            s += f.x * f.x + f.y * f.y + f.z * f.z + f.w * f.w;
        }
        sInv[tid] = rsqrtf(s);
    }
    __syncthreads();
    {
        int lr = tid & 63, seg = tid >> 6;
        float inv = sInv[lr];
        const float* wr = fcw + (size_t)(c0 + lr) * 256 + seg * 64;
        unsigned short* dst = &sW[lr][seg * 64];
        for (int k = 0; k < 64; k += 4) {
            float4 f = *(const float4*)(wr + k);
            dst[k + 0] = f2bf(f.x * inv); dst[k + 1] = f2bf(f.y * inv);
            dst[k + 2] = f2bf(f.z * inv); dst[k + 3] = f2bf(f.w * inv);
        }
    }
    __syncthreads();
    const int lane = tid & 63, w = tid >> 6, q = lane >> 4, ln = lane & 15;
    f32x4 acc[2][4];
    for (int rk = 0; rk < 2; ++rk)
        for (int nb = 0; nb < 4; ++nb) {
            float bv = fcb[c0 + nb * 16 + ln];
            acc[rk][nb] = (f32x4){bv, bv, bv, bv};
        }
    const unsigned short* ap = h2s + (size_t)rb * (Bt * Vt);
    for (int kb = 0; kb < 8; ++kb) {
        bf16x8 a0 = *(const bf16x8*)(ap + (32 * w + ln) * 256 + kb * 32 + q * 8);
        bf16x8 a1 = *(const bf16x8*)(ap + (32 * w + 16 + ln) * 256 + kb * 32 + q * 8);
        for (int nb = 0; nb < 4; ++nb) {
            bf16x8 b = *(const bf16x8*)&sW[nb * 16 + ln][kb * 32 + q * 8];
            acc[0][nb] = MFMA(a0, b, acc[0][nb]);
            acc[1][nb] = MFMA(a1, b, acc[1][nb]);
        }
    }
    for (int rk = 0; rk < 2; ++rk)
        for (int nb = 0; nb < 4; ++nb)
            for (int r = 0; r < 4; ++r) {
                int bb = 32 * w + rk * 16 + q * 4 + r;
                int o = c0 + nb * 16 + ln;
                out[((size_t)bb * Tt + rb) * 256 + o] = acc[rk][nb][r];
            }
}

extern "C" void kernel_launch(void* const* d_in, const int* in_sizes, int n_in,
                              void* d_out, int out_size, void* d_ws, size_t ws_size,
                              hipStream_t stream) {
    const float* x    = (const float*)d_in[0];
    const float* Wih1 = (const float*)d_in[1];
    const float* Whh1 = (const float*)d_in[2];
    const float* bih1 = (const float*)d_in[3];
    const float* bhh1 = (const float*)d_in[4];
    const float* Wih2 = (const float*)d_in[5];
    const float* Whh2 = (const float*)d_in[6];
    const float* bih2 = (const float*)d_in[7];
    const float* bhh2 = (const float*)d_in[8];
    const float* fcw  = (const float*)d_in[9];
    const float* fcb  = (const float*)d_in[10];

    char* ws = (char*)d_ws;
    unsigned int* prog1 = (unsigned int*)ws;   // 128 words: [wg][wave]
    unsigned int* prog2 = prog1 + 128;         // 128 words
    unsigned short* xT  = (unsigned short*)(ws + 16384);
    unsigned short* h1s = xT + (size_t)Tt * Bt * Vt;
    unsigned short* h2s = h1s + (size_t)Tt * Bt * Vt;

    hipMemsetAsync(ws, 0, 16384, stream);
    cvt_kernel<<<16384, 256, 0, stream>>>(x, xT);
    rec_kernel<<<64, 256, 0, stream>>>(Wih1, Whh1, bih1, bhh1,
                                       Wih2, Whh2, bih2, bhh2,
                                       xT, h1s, h2s, prog1, prog2);
    fc_kernel<<<4096, 256, 0, stream>>>(h2s, fcw, fcb, (float*)d_out);
}

// Round 3
// 8439.032 us; speedup vs baseline: 1.3029x; 1.0623x over previous
//
#include <hip/hip_runtime.h>
#include <stdint.h>

#define Tt 1024
#define Bt 128
#define Vt 256

typedef __attribute__((ext_vector_type(8))) short bf16x8;
typedef __attribute__((ext_vector_type(4))) float f32x4;
typedef __attribute__((ext_vector_type(4))) int i32x4;

#define MFMA(a, b, c) __builtin_amdgcn_mfma_f32_16x16x32_bf16(a, b, c, 0, 0, 0)

// Sentinel = bf16 +NaN (0x7FFF). h = o*tanh(c) is finite in (-1,1); f2bf of a
// finite float can never produce 0x7FFF, so it uniquely marks "not yet written".
#define SENT 0x7FFF

__device__ __forceinline__ unsigned short f2bf(float f) {
    unsigned u = __builtin_bit_cast(unsigned, f);
    u += 0x7fffu + ((u >> 16) & 1u);
    return (unsigned short)(u >> 16);
}
__device__ __forceinline__ float sigm(float x) {
    return __builtin_amdgcn_rcpf(1.f + __expf(-x));
}
__device__ __forceinline__ float tanh_f(float x) {
    float e = __expf(-2.f * fabsf(x));
    float t = (1.f - e) * __builtin_amdgcn_rcpf(1.f + e);
    return copysignf(t, x);
}

// agent-coherent 16B load (sc0 sc1 = bypass L1+L2, read at MALL). No wait
// attached; caller batches then drains once.
template <int OFF>
__device__ __forceinline__ bf16x8 ldcc(const unsigned short* p) {
    bf16x8 d;
    asm volatile("global_load_dwordx4 %0, %1, off offset:%c2 sc0 sc1"
                 : "=v"(d)
                 : "v"(p), "i"(OFF));
    return d;
}
#define LDROW(dst, p)                                  \
    do {                                               \
        dst[0] = ldcc<0>(p);   dst[1] = ldcc<64>(p);   \
        dst[2] = ldcc<128>(p); dst[3] = ldcc<192>(p);  \
        dst[4] = ldcc<256>(p); dst[5] = ldcc<320>(p);  \
        dst[6] = ldcc<384>(p); dst[7] = ldcc<448>(p);  \
    } while (0)

__device__ __forceinline__ void vm_drain() {
    asm volatile("s_waitcnt vmcnt(0)" ::: "memory");
    __builtin_amdgcn_sched_barrier(0);  // rule #18: keep MFMAs below the wait
}

// Each 16B fragment is written by exactly two 8B single-lane stores (atomic
// each). Checking one short per 8B half (s[0] -> d.x low, s[4] -> d.z low)
// covers both halves.
__device__ __forceinline__ int fdirty(bf16x8 f) {
    i32x4 d = __builtin_bit_cast(i32x4, f);
    return ((d.x & 0xFFFF) == SENT) | ((d.z & 0xFFFF) == SENT);
}

// ---------------- x [B,T,V] fp32 -> xT [T,B,V] bf16 ----------------
__global__ __launch_bounds__(256) void cvt_kernel(const float* __restrict__ x,
                                                  unsigned short* __restrict__ xT) {
    unsigned g = blockIdx.x * 256u + threadIdx.x;
    unsigned base = g * 8u;
    unsigned r = base >> 8;  // r = t*128 + b
    unsigned v = base & 255u;
    unsigned t = r >> 7, b = r & 127u;
    const float4* src = (const float4*)(x + ((size_t)b * Tt + t) * Vt + v);
    float4 f0 = src[0], f1 = src[1];
    union { unsigned short s[8]; int4 q; } o;
    o.s[0] = f2bf(f0.x); o.s[1] = f2bf(f0.y); o.s[2] = f2bf(f0.z); o.s[3] = f2bf(f0.w);
    o.s[4] = f2bf(f1.x); o.s[5] = f2bf(f1.y); o.s[6] = f2bf(f1.z); o.s[7] = f2bf(f1.w);
    *(int4*)(xT + (size_t)r * Vt + v) = o.q;
}

// ---------------- sentinel pre-fill of h1s+h2s (contiguous 128MB) ----------
// Must write through to MALL (sc0 sc1): pollers read MALL directly; a value
// parked dirty in an XCD L2 would leave them seeing stale garbage.
__global__ __launch_bounds__(256) void fill_kernel(unsigned short* __restrict__ h) {
    size_t i = ((size_t)blockIdx.x * 256u + threadIdx.x) * 16u;  // shorts
    i32x4 s = (i32x4){0x7FFF7FFF, 0x7FFF7FFF, 0x7FFF7FFF, 0x7FFF7FFF};
    asm volatile("global_store_dwordx4 %0, %1, off sc0 sc1" ::"v"(h + i), "v"(s) : "memory");
    asm volatile("global_store_dwordx4 %0, %1, off offset:16 sc0 sc1" ::"v"(h + i), "v"(s) : "memory");
}

// ---------------- persistent dataflow recurrence: 64 WGs ----------------
// wg 0..31 : layer 1, owns h-cols [8*sub, 8*sub+8); wg 32..63 : layer 2.
// Wave w of every WG is an independent pipeline over batch rows [32w,32w+32).
// No flags: consumers poll the h data itself for the sentinel; producers just
// store (no ack, no signal). Detect+load = one MALL round trip.
__global__ __launch_bounds__(256) void rec_kernel(
    const float* __restrict__ Wih1, const float* __restrict__ Whh1,
    const float* __restrict__ bih1, const float* __restrict__ bhh1,
    const float* __restrict__ Wih2, const float* __restrict__ Whh2,
    const float* __restrict__ bih2, const float* __restrict__ bhh2,
    const unsigned short* __restrict__ xT,
    unsigned short* h1s, unsigned short* h2s) {
    const int wg = blockIdx.x;
    const int layer = wg >> 5;
    const int sub = wg & 31;
    const int hc0 = sub * 8;
    const float* Win = layer ? Wih2 : Wih1;
    const float* Whh = layer ? Whh2 : Whh1;
    const float* bi = layer ? bih2 : bih1;
    const float* bh = layer ? bhh2 : bhh1;

    __shared__ unsigned short sWin[32][264];
    __shared__ unsigned short sWhh[32][264];
    __shared__ unsigned short sH[128][8];  // per-wave-private rows [32w,32w+32)

    const int tid = threadIdx.x;
    {
        int m = tid >> 7;  // 0: Win, 1: Whh
        int lr = (tid >> 2) & 31;
        int seg = tid & 3;
        int grp = lr >> 3, local = lr & 7;
        int grow = 256 * grp + hc0 + local;
        const float* src = (m ? Whh : Win) + (size_t)grow * Vt + seg * 64;
        unsigned short* dst = m ? &sWhh[lr][seg * 64] : &sWin[lr][seg * 64];
        for (int k = 0; k < 64; k += 4) {
            float4 f = *(const float4*)(src + k);
            dst[k + 0] = f2bf(f.x); dst[k + 1] = f2bf(f.y);
            dst[k + 2] = f2bf(f.z); dst[k + 3] = f2bf(f.w);
        }
    }
    __syncthreads();  // only barrier: weights staged

    const int lane = tid & 63;
    const int w = tid >> 6;
    const int q = lane >> 4;
    const int ln = lane & 15;

    float biasv[2];
    for (int nb = 0; nb < 2; ++nb) {
        int grp = nb * 2 + (ln >> 3);
        int grow = 256 * grp + hc0 + (ln & 7);
        biasv[nb] = bi[grow] + bh[grow];
    }

    float cst[2][4];
#pragma unroll
    for (int rb = 0; rb < 2; ++rb)
#pragma unroll
        for (int r = 0; r < 4; ++r) cst[rb][r] = 0.f;

    const int rowoff0 = (32 * w + ln) * 256 + q * 8;
    const int rowoff1 = rowoff0 + 16 * 256;

    unsigned short* obbase = layer ? h2s : h1s;

    // store-back lane mapping: lane l -> row 32w + (l>>1), 8B half (l&1)
    const int srow = 32 * w + (lane >> 1);
    const int shalf = lane & 1;
    unsigned short* obptr0 = obbase + (size_t)srow * 256 + hc0 + shalf * 4;

    for (int t = 0; t < Tt; ++t) {
        f32x4 acc[2][2];
#pragma unroll
        for (int rb = 0; rb < 2; ++rb)
#pragma unroll
            for (int nb = 0; nb < 2; ++nb)
                acc[rb][nb] = (f32x4){biasv[nb], biasv[nb], biasv[nb], biasv[nb]};

        if (layer == 0) {
            const unsigned short* hp = h1s + (size_t)(t - 1) * (Bt * Vt);
            bf16x8 ah0[8], ah1[8];
            if (t > 0) {  // issue poll loads first: flight hides under x GEMM
                LDROW(ah0, hp + rowoff0);
                LDROW(ah1, hp + rowoff1);
            }
            // x-proj GEMM (independent of the recurrence)
            const unsigned short* xp = xT + (size_t)t * (Bt * Vt);
            bf16x8 ax0[8], ax1[8];
#pragma unroll
            for (int kb = 0; kb < 8; ++kb) {
                ax0[kb] = *(const bf16x8*)(xp + rowoff0 + kb * 32);
                ax1[kb] = *(const bf16x8*)(xp + rowoff1 + kb * 32);
            }
#pragma unroll
            for (int kb = 0; kb < 8; ++kb) {
                bf16x8 b0 = *(const bf16x8*)&sWin[ln][kb * 32 + q * 8];
                bf16x8 b1 = *(const bf16x8*)&sWin[16 + ln][kb * 32 + q * 8];
                acc[0][0] = MFMA(ax0[kb], b0, acc[0][0]);
                acc[1][0] = MFMA(ax1[kb], b0, acc[1][0]);
                acc[0][1] = MFMA(ax0[kb], b1, acc[0][1]);
                acc[1][1] = MFMA(ax1[kb], b1, acc[1][1]);
            }
            if (t > 0) {
                for (;;) {  // sentinel poll: when clean, data already in regs
                    vm_drain();
                    int d = 0;
#pragma unroll
                    for (int kb = 0; kb < 8; ++kb) d |= fdirty(ah0[kb]) | fdirty(ah1[kb]);
                    if (!__any(d)) break;
                    __builtin_amdgcn_s_sleep(1);
                    LDROW(ah0, hp + rowoff0);
                    LDROW(ah1, hp + rowoff1);
                }
#pragma unroll
                for (int kb = 0; kb < 8; ++kb) {
                    bf16x8 b0 = *(const bf16x8*)&sWhh[ln][kb * 32 + q * 8];
                    bf16x8 b1 = *(const bf16x8*)&sWhh[16 + ln][kb * 32 + q * 8];
                    acc[0][0] = MFMA(ah0[kb], b0, acc[0][0]);
                    acc[1][0] = MFMA(ah1[kb], b0, acc[1][0]);
                    acc[0][1] = MFMA(ah0[kb], b1, acc[0][1]);
                    acc[1][1] = MFMA(ah1[kb], b1, acc[1][1]);
                }
            }
        } else {
            const unsigned short* hp1 = h1s + (size_t)t * (Bt * Vt);
            const unsigned short* hp2 = h2s + (size_t)(t - 1) * (Bt * Vt);
            bf16x8 ai0[8], ai1[8], ah0[8], ah1[8];
            LDROW(ai0, hp1 + rowoff0);
            LDROW(ai1, hp1 + rowoff1);
            if (t > 0) {
                LDROW(ah0, hp2 + rowoff0);
                LDROW(ah1, hp2 + rowoff1);
            }
            for (;;) {  // combined poll: one wait for both operand sets
                vm_drain();
                int d = 0;
#pragma unroll
                for (int kb = 0; kb < 8; ++kb) d |= fdirty(ai0[kb]) | fdirty(ai1[kb]);
                if (t > 0) {
#pragma unroll
                    for (int kb = 0; kb < 8; ++kb) d |= fdirty(ah0[kb]) | fdirty(ah1[kb]);
                }
                if (!__any(d)) break;
                __builtin_amdgcn_s_sleep(1);
                LDROW(ai0, hp1 + rowoff0);
                LDROW(ai1, hp1 + rowoff1);
                if (t > 0) {
                    LDROW(ah0, hp2 + rowoff0);
                    LDROW(ah1, hp2 + rowoff1);
                }
            }
#pragma unroll
            for (int kb = 0; kb < 8; ++kb) {
                bf16x8 b0 = *(const bf16x8*)&sWin[ln][kb * 32 + q * 8];
                bf16x8 b1 = *(const bf16x8*)&sWin[16 + ln][kb * 32 + q * 8];
                acc[0][0] = MFMA(ai0[kb], b0, acc[0][0]);
                acc[1][0] = MFMA(ai1[kb], b0, acc[1][0]);
                acc[0][1] = MFMA(ai0[kb], b1, acc[0][1]);
                acc[1][1] = MFMA(ai1[kb], b1, acc[1][1]);
            }
            if (t > 0) {
#pragma unroll
                for (int kb = 0; kb < 8; ++kb) {
                    bf16x8 b0 = *(const bf16x8*)&sWhh[ln][kb * 32 + q * 8];
                    bf16x8 b1 = *(const bf16x8*)&sWhh[16 + ln][kb * 32 + q * 8];
                    acc[0][0] = MFMA(ah0[kb], b0, acc[0][0]);
                    acc[1][0] = MFMA(ah1[kb], b0, acc[1][0]);
                    acc[0][1] = MFMA(ah0[kb], b1, acc[0][1]);
                    acc[1][1] = MFMA(ah1[kb], b1, acc[1][1]);
                }
            }
        }

        // elementwise LSTM cell; lane ln holds (i|f) in acc[.][0], (g|o) in acc[.][1]
#pragma unroll
        for (int rb = 0; rb < 2; ++rb) {
#pragma unroll
            for (int r = 0; r < 4; ++r) {
                float a0 = acc[rb][0][r], a1 = acc[rb][1][r];
                float b0 = __shfl_xor(a0, 8);
                float b1 = __shfl_xor(a1, 8);
                float iv, fv, gv, ov;
                if (ln < 8) { iv = a0; fv = b0; gv = a1; ov = b1; }
                else        { iv = b0; fv = a0; gv = b1; ov = a1; }
                float ii = sigm(iv), ff = sigm(fv), gg = tanh_f(gv), oo = sigm(ov);
                float cc = ff * cst[rb][r] + ii * gg;
                cst[rb][r] = cc;
                float hh = oo * tanh_f(cc);
                if (ln < 8) sH[32 * w + rb * 16 + q * 4 + r][ln] = f2bf(hh);
            }
        }
        // wave-local LDS transpose: cross-lane within a wave -> lgkmcnt only
        asm volatile("s_waitcnt lgkmcnt(0)" ::: "memory");
        __builtin_amdgcn_sched_barrier(0);
        unsigned long long hv = *(const unsigned long long*)&sH[srow][shalf * 4];
        unsigned short* dst = obptr0 + (size_t)t * (Bt * Vt);
        // fire-and-forget: no ack, no signal. Consumers detect via sentinel.
        asm volatile("global_store_dwordx2 %0, %1, off sc0 sc1" ::"v"(dst), "v"(hv)
                     : "memory");
    }
}

// ---------------- out[b,t,:] = h2s[t,b,:] @ w_n^T + fc_b ----------------
__global__ __launch_bounds__(256) void fc_kernel(const unsigned short* __restrict__ h2s,
                                                 const float* __restrict__ fcw,
                                                 const float* __restrict__ fcb,
                                                 float* __restrict__ out) {
    const int bid = blockIdx.x;
    const int rb = bid >> 2;  // t
    const int c0 = (bid & 3) * 64;
    __shared__ unsigned short sW[64][264];
    __shared__ float sInv[64];
    const int tid = threadIdx.x;
    if (tid < 64) {
        const float* wr = fcw + (size_t)(c0 + tid) * 256;
        float s = 0.f;
        for (int k = 0; k < 256; k += 4) {
            float4 f = *(const float4*)(wr + k);
            s += f.x * f.x + f.y * f.y + f.z * f.z + f.w * f.w;
        }
        sInv[tid] = rsqrtf(s);
    }
    __syncthreads();
    {
        int lr = tid & 63, seg = tid >> 6;
        float inv = sInv[lr];
        const float* wr = fcw + (size_t)(c0 + lr) * 256 + seg * 64;
        unsigned short* dst = &sW[lr][seg * 64];
        for (int k = 0; k < 64; k += 4) {
            float4 f = *(const float4*)(wr + k);
            dst[k + 0] = f2bf(f.x * inv); dst[k + 1] = f2bf(f.y * inv);
            dst[k + 2] = f2bf(f.z * inv); dst[k + 3] = f2bf(f.w * inv);
        }
    }
    __syncthreads();
    const int lane = tid & 63, w = tid >> 6, q = lane >> 4, ln = lane & 15;
    f32x4 acc[2][4];
    for (int rk = 0; rk < 2; ++rk)
        for (int nb = 0; nb < 4; ++nb) {
            float bv = fcb[c0 + nb * 16 + ln];
            acc[rk][nb] = (f32x4){bv, bv, bv, bv};
        }
    const unsigned short* ap = h2s + (size_t)rb * (Bt * Vt);
    for (int kb = 0; kb < 8; ++kb) {
        bf16x8 a0 = *(const bf16x8*)(ap + (32 * w + ln) * 256 + kb * 32 + q * 8);
        bf16x8 a1 = *(const bf16x8*)(ap + (32 * w + 16 + ln) * 256 + kb * 32 + q * 8);
        for (int nb = 0; nb < 4; ++nb) {
            bf16x8 b = *(const bf16x8*)&sW[nb * 16 + ln][kb * 32 + q * 8];
            acc[0][nb] = MFMA(a0, b, acc[0][nb]);
            acc[1][nb] = MFMA(a1, b, acc[1][nb]);
        }
    }
    for (int rk = 0; rk < 2; ++rk)
        for (int nb = 0; nb < 4; ++nb)
            for (int r = 0; r < 4; ++r) {
                int bb = 32 * w + rk * 16 + q * 4 + r;
                int o = c0 + nb * 16 + ln;
                out[((size_t)bb * Tt + rb) * 256 + o] = acc[rk][nb][r];
            }
}

extern "C" void kernel_launch(void* const* d_in, const int* in_sizes, int n_in,
                              void* d_out, int out_size, void* d_ws, size_t ws_size,
                              hipStream_t stream) {
    const float* x    = (const float*)d_in[0];
    const float* Wih1 = (const float*)d_in[1];
    const float* Whh1 = (const float*)d_in[2];
    const float* bih1 = (const float*)d_in[3];
    const float* bhh1 = (const float*)d_in[4];
    const float* Wih2 = (const float*)d_in[5];
    const float* Whh2 = (const float*)d_in[6];
    const float* bih2 = (const float*)d_in[7];
    const float* bhh2 = (const float*)d_in[8];
    const float* fcw  = (const float*)d_in[9];
    const float* fcb  = (const float*)d_in[10];

    char* ws = (char*)d_ws;
    unsigned short* xT  = (unsigned short*)ws;
    unsigned short* h1s = xT + (size_t)Tt * Bt * Vt;
    unsigned short* h2s = h1s + (size_t)Tt * Bt * Vt;

    fill_kernel<<<16384, 256, 0, stream>>>(h1s);  // h1s+h2s contiguous
    cvt_kernel<<<16384, 256, 0, stream>>>(x, xT);
    rec_kernel<<<64, 256, 0, stream>>>(Wih1, Whh1, bih1, bhh1,
                                       Wih2, Whh2, bih2, bhh2,
                                       xT, h1s, h2s);
    fc_kernel<<<4096, 256, 0, stream>>>(h2s, fcw, fcb, (float*)d_out);
}

// Round 4
// 5922.524 us; speedup vs baseline: 1.8565x; 1.4249x over previous
//
#include <hip/hip_runtime.h>
#include <stdint.h>

#define Tt 1024
#define Bt 128
#define Vt 256
#define TSLICE (Bt * Vt)  // shorts per t-slice (32768)

typedef __attribute__((ext_vector_type(8))) short bf16x8;
typedef __attribute__((ext_vector_type(4))) float f32x4;
typedef __attribute__((ext_vector_type(4))) int i32x4;

#define MFMA(a, b, c) __builtin_amdgcn_mfma_f32_16x16x32_bf16(a, b, c, 0, 0, 0)

// Sentinel = bf16 +NaN (0x7FFF). h = o*tanh(c) is finite in (-1,1); f2bf of a
// finite float can never produce 0x7FFF, so it uniquely marks "not yet written".
#define SENT 0x7FFF

// h layout (tiled, the key change this round):
//   h[t][w][s][row][col]  w=wave 0..3, s=col-block 0..31, tile = 32 rows x 8 cols
//   shorts offset = t*TSLICE + w*8192 + s*256 + row*8 + col
// Producer wave (layer,s,w): lane L stores 8B at tile offset L*4 shorts ->
// ONE fully-coalesced 512B store per wave (was 64 scattered 8B transactions).
// Consumer wave w: A-fragment (rb,kb,q,ln) = tile s=kb*4+q, row rb*16+ln ->
// per-lane ptr P = region + q*256 + ln*8, frag at P + kb*1024 + rb*128 shorts.

__device__ __forceinline__ unsigned short f2bf(float f) {
    unsigned u = __builtin_bit_cast(unsigned, f);
    u += 0x7fffu + ((u >> 16) & 1u);
    return (unsigned short)(u >> 16);
}
__device__ __forceinline__ float sigm(float x) {
    return __builtin_amdgcn_rcpf(1.f + __expf(-x));
}
__device__ __forceinline__ float tanh_f(float x) {
    float e = __expf(-2.f * fabsf(x));
    float t = (1.f - e) * __builtin_amdgcn_rcpf(1.f + e);
    return copysignf(t, x);
}

// agent-coherent 16B load (sc0 sc1 = bypass L1+L2, read at MALL). No wait
// attached; caller batches then drains once. OFF is in BYTES.
template <int OFF>
__device__ __forceinline__ bf16x8 ldcc(const unsigned short* p) {
    bf16x8 d;
    asm volatile("global_load_dwordx4 %0, %1, off offset:%c2 sc0 sc1"
                 : "=v"(d)
                 : "v"(p), "i"(OFF));
    return d;
}
// load both rb-fragments of all 8 kb tiles for one operand region
#define LDTILES(d0, d1, P)                                    \
    do {                                                      \
        _Pragma("unroll") for (int kb = 0; kb < 8; ++kb) {    \
            const unsigned short* pk = (P) + kb * 1024;       \
            d0[kb] = ldcc<0>(pk);                             \
            d1[kb] = ldcc<256>(pk);                           \
        }                                                     \
    } while (0)

__device__ __forceinline__ void vm_drain() {
    asm volatile("s_waitcnt vmcnt(0)" ::: "memory");
    __builtin_amdgcn_sched_barrier(0);  // rule #18: keep MFMAs below the wait
}

// Each 16B fragment = two 8B halves written by two lanes of one producer wave
// store (each 8B lane-store atomic). Check one short per half.
__device__ __forceinline__ int fdirty(bf16x8 f) {
    i32x4 d = __builtin_bit_cast(i32x4, f);
    return ((d.x & 0xFFFF) == SENT) | ((d.z & 0xFFFF) == SENT);
}

// ---------------- x [B,T,V] fp32 -> xT [T,B,V] bf16 ----------------
__global__ __launch_bounds__(256) void cvt_kernel(const float* __restrict__ x,
                                                  unsigned short* __restrict__ xT) {
    unsigned g = blockIdx.x * 256u + threadIdx.x;
    unsigned base = g * 8u;
    unsigned r = base >> 8;  // r = t*128 + b
    unsigned v = base & 255u;
    unsigned t = r >> 7, b = r & 127u;
    const float4* src = (const float4*)(x + ((size_t)b * Tt + t) * Vt + v);
    float4 f0 = src[0], f1 = src[1];
    union { unsigned short s[8]; int4 q; } o;
    o.s[0] = f2bf(f0.x); o.s[1] = f2bf(f0.y); o.s[2] = f2bf(f0.z); o.s[3] = f2bf(f0.w);
    o.s[4] = f2bf(f1.x); o.s[5] = f2bf(f1.y); o.s[6] = f2bf(f1.z); o.s[7] = f2bf(f1.w);
    *(int4*)(xT + (size_t)r * Vt + v) = o.q;
}

// ---------------- sentinel pre-fill of h1s+h2s (contiguous 128MB) ----------
__global__ __launch_bounds__(256) void fill_kernel(unsigned short* __restrict__ h) {
    size_t i = ((size_t)blockIdx.x * 256u + threadIdx.x) * 16u;  // shorts
    i32x4 s = (i32x4){0x7FFF7FFF, 0x7FFF7FFF, 0x7FFF7FFF, 0x7FFF7FFF};
    asm volatile("global_store_dwordx4 %0, %1, off sc0 sc1" ::"v"(h + i), "v"(s) : "memory");
    asm volatile("global_store_dwordx4 %0, %1, off offset:16 sc0 sc1" ::"v"(h + i), "v"(s) : "memory");
}

// ---------------- persistent dataflow recurrence: 64 WGs ----------------
__global__ __launch_bounds__(256) void rec_kernel(
    const float* __restrict__ Wih1, const float* __restrict__ Whh1,
    const float* __restrict__ bih1, const float* __restrict__ bhh1,
    const float* __restrict__ Wih2, const float* __restrict__ Whh2,
    const float* __restrict__ bih2, const float* __restrict__ bhh2,
    const unsigned short* __restrict__ xT,
    unsigned short* h1s, unsigned short* h2s) {
    const int wg = blockIdx.x;
    const int layer = wg >> 5;
    const int sub = wg & 31;
    const int hc0 = sub * 8;
    const float* Win = layer ? Wih2 : Wih1;
    const float* Whh = layer ? Whh2 : Whh1;
    const float* bi = layer ? bih2 : bih1;
    const float* bh = layer ? bhh2 : bhh1;

    __shared__ unsigned short sWin[32][264];
    __shared__ unsigned short sWhh[32][264];
    __shared__ unsigned short sH[128][8];  // per-wave-private rows [32w,32w+32)

    const int tid = threadIdx.x;
    {
        int m = tid >> 7;  // 0: Win, 1: Whh
        int lr = (tid >> 2) & 31;
        int seg = tid & 3;
        int grp = lr >> 3, local = lr & 7;
        int grow = 256 * grp + hc0 + local;
        const float* src = (m ? Whh : Win) + (size_t)grow * Vt + seg * 64;
        unsigned short* dst = m ? &sWhh[lr][seg * 64] : &sWin[lr][seg * 64];
        for (int k = 0; k < 64; k += 4) {
            float4 f = *(const float4*)(src + k);
            dst[k + 0] = f2bf(f.x); dst[k + 1] = f2bf(f.y);
            dst[k + 2] = f2bf(f.z); dst[k + 3] = f2bf(f.w);
        }
    }
    __syncthreads();  // only barrier: weights staged

    const int lane = tid & 63;
    const int w = tid >> 6;
    const int q = lane >> 4;
    const int ln = lane & 15;

    float biasv[2];
    for (int nb = 0; nb < 2; ++nb) {
        int grp = nb * 2 + (ln >> 3);
        int grow = 256 * grp + hc0 + (ln & 7);
        biasv[nb] = bi[grow] + bh[grow];
    }

    float cst[2][4];
#pragma unroll
    for (int rb = 0; rb < 2; ++rb)
#pragma unroll
        for (int r = 0; r < 4; ++r) cst[rb][r] = 0.f;

    // xT stays row-major [t][b][v]
    const int rowoff0 = (32 * w + ln) * 256 + q * 8;
    const int rowoff1 = rowoff0 + 16 * 256;
    // tiled-h per-lane consumer offset within region
    const int coff = q * 256 + ln * 8;

    unsigned short* obbase = layer ? h2s : h1s;
    // producer: contiguous 512B tile store, lane L -> offset L*4 shorts
    unsigned short* obptr0 = obbase + w * 8192 + sub * 256 + lane * 4;

    for (int t = 0; t < Tt; ++t) {
        f32x4 acc[2][2];
#pragma unroll
        for (int rb = 0; rb < 2; ++rb)
#pragma unroll
            for (int nb = 0; nb < 2; ++nb)
                acc[rb][nb] = (f32x4){biasv[nb], biasv[nb], biasv[nb], biasv[nb]};

        if (layer == 0) {
            const unsigned short* hP =
                h1s + (size_t)(t - 1) * TSLICE + w * 8192 + coff;
            bf16x8 ah0[8], ah1[8];
            if (t > 0) {  // issue poll loads first: flight hides under x GEMM
                LDTILES(ah0, ah1, hP);
            }
            // x-proj GEMM (independent of the recurrence)
            const unsigned short* xp = xT + (size_t)t * TSLICE;
            bf16x8 ax0[8], ax1[8];
#pragma unroll
            for (int kb = 0; kb < 8; ++kb) {
                ax0[kb] = *(const bf16x8*)(xp + rowoff0 + kb * 32);
                ax1[kb] = *(const bf16x8*)(xp + rowoff1 + kb * 32);
            }
#pragma unroll
            for (int kb = 0; kb < 8; ++kb) {
                bf16x8 b0 = *(const bf16x8*)&sWin[ln][kb * 32 + q * 8];
                bf16x8 b1 = *(const bf16x8*)&sWin[16 + ln][kb * 32 + q * 8];
                acc[0][0] = MFMA(ax0[kb], b0, acc[0][0]);
                acc[1][0] = MFMA(ax1[kb], b0, acc[1][0]);
                acc[0][1] = MFMA(ax0[kb], b1, acc[0][1]);
                acc[1][1] = MFMA(ax1[kb], b1, acc[1][1]);
            }
            if (t > 0) {
                for (;;) {  // sentinel poll: when clean, data already in regs
                    vm_drain();
                    int d = 0;
#pragma unroll
                    for (int kb = 0; kb < 8; ++kb) d |= fdirty(ah0[kb]) | fdirty(ah1[kb]);
                    if (!__any(d)) break;
                    __builtin_amdgcn_s_sleep(1);
                    LDTILES(ah0, ah1, hP);
                }
#pragma unroll
                for (int kb = 0; kb < 8; ++kb) {
                    bf16x8 b0 = *(const bf16x8*)&sWhh[ln][kb * 32 + q * 8];
                    bf16x8 b1 = *(const bf16x8*)&sWhh[16 + ln][kb * 32 + q * 8];
                    acc[0][0] = MFMA(ah0[kb], b0, acc[0][0]);
                    acc[1][0] = MFMA(ah1[kb], b0, acc[1][0]);
                    acc[0][1] = MFMA(ah0[kb], b1, acc[0][1]);
                    acc[1][1] = MFMA(ah1[kb], b1, acc[1][1]);
                }
            }
        } else {
            const unsigned short* hP1 =
                h1s + (size_t)t * TSLICE + w * 8192 + coff;
            const unsigned short* hP2 =
                h2s + (size_t)(t - 1) * TSLICE + w * 8192 + coff;
            bf16x8 ai0[8], ai1[8], ah0[8], ah1[8];
            LDTILES(ai0, ai1, hP1);
            if (t > 0) {
                LDTILES(ah0, ah1, hP2);
            }
            for (;;) {  // combined poll: one wait for both operand sets
                vm_drain();
                int d = 0;
#pragma unroll
                for (int kb = 0; kb < 8; ++kb) d |= fdirty(ai0[kb]) | fdirty(ai1[kb]);
                if (t > 0) {
#pragma unroll
                    for (int kb = 0; kb < 8; ++kb) d |= fdirty(ah0[kb]) | fdirty(ah1[kb]);
                }
                if (!__any(d)) break;
                __builtin_amdgcn_s_sleep(1);
                LDTILES(ai0, ai1, hP1);
                if (t > 0) {
                    LDTILES(ah0, ah1, hP2);
                }
            }
#pragma unroll
            for (int kb = 0; kb < 8; ++kb) {
                bf16x8 b0 = *(const bf16x8*)&sWin[ln][kb * 32 + q * 8];
                bf16x8 b1 = *(const bf16x8*)&sWin[16 + ln][kb * 32 + q * 8];
                acc[0][0] = MFMA(ai0[kb], b0, acc[0][0]);
                acc[1][0] = MFMA(ai1[kb], b0, acc[1][0]);
                acc[0][1] = MFMA(ai0[kb], b1, acc[0][1]);
                acc[1][1] = MFMA(ai1[kb], b1, acc[1][1]);
            }
            if (t > 0) {
#pragma unroll
                for (int kb = 0; kb < 8; ++kb) {
                    bf16x8 b0 = *(const bf16x8*)&sWhh[ln][kb * 32 + q * 8];
                    bf16x8 b1 = *(const bf16x8*)&sWhh[16 + ln][kb * 32 + q * 8];
                    acc[0][0] = MFMA(ah0[kb], b0, acc[0][0]);
                    acc[1][0] = MFMA(ah1[kb], b0, acc[1][0]);
                    acc[0][1] = MFMA(ah0[kb], b1, acc[0][1]);
                    acc[1][1] = MFMA(ah1[kb], b1, acc[1][1]);
                }
            }
        }

        // elementwise LSTM cell; lane ln holds (i|f) in acc[.][0], (g|o) in acc[.][1]
#pragma unroll
        for (int rb = 0; rb < 2; ++rb) {
#pragma unroll
            for (int r = 0; r < 4; ++r) {
                float a0 = acc[rb][0][r], a1 = acc[rb][1][r];
                float b0 = __shfl_xor(a0, 8);
                float b1 = __shfl_xor(a1, 8);
                float iv, fv, gv, ov;
                if (ln < 8) { iv = a0; fv = b0; gv = a1; ov = b1; }
                else        { iv = b0; fv = a0; gv = b1; ov = a1; }
                float ii = sigm(iv), ff = sigm(fv), gg = tanh_f(gv), oo = sigm(ov);
                float cc = ff * cst[rb][r] + ii * gg;
                cst[rb][r] = cc;
                float hh = oo * tanh_f(cc);
                if (ln < 8) sH[32 * w + rb * 16 + q * 4 + r][ln] = f2bf(hh);
            }
        }
        // wave-local LDS transpose: cross-lane within a wave -> lgkmcnt only
        asm volatile("s_waitcnt lgkmcnt(0)" ::: "memory");
        __builtin_amdgcn_sched_barrier(0);
        // lane L: row 32w+(L>>1), col-half (L&1) -> tile offset L*4 shorts
        unsigned long long hv =
            *(const unsigned long long*)&sH[32 * w + (lane >> 1)][(lane & 1) * 4];
        unsigned short* dst = obptr0 + (size_t)t * TSLICE;
        // fire-and-forget coalesced 512B wave store; consumers detect sentinel
        asm volatile("global_store_dwordx2 %0, %1, off sc0 sc1" ::"v"(dst), "v"(hv)
                     : "memory");
    }
}

// ---------------- out[b,t,:] = h2s_tiled[t] @ w_n^T + fc_b ----------------
__global__ __launch_bounds__(256) void fc_kernel(const unsigned short* __restrict__ h2s,
                                                 const float* __restrict__ fcw,
                                                 const float* __restrict__ fcb,
                                                 float* __restrict__ out) {
    const int bid = blockIdx.x;
    const int rb = bid >> 2;  // t
    const int c0 = (bid & 3) * 64;
    __shared__ unsigned short sW[64][264];
    __shared__ float sInv[64];
    const int tid = threadIdx.x;
    if (tid < 64) {
        const float* wr = fcw + (size_t)(c0 + tid) * 256;
        float s = 0.f;
        for (int k = 0; k < 256; k += 4) {
            float4 f = *(const float4*)(wr + k);
            s += f.x * f.x + f.y * f.y + f.z * f.z + f.w * f.w;
        }
        sInv[tid] = rsqrtf(s);
    }
    __syncthreads();
    {
        int lr = tid & 63, seg = tid >> 6;
        float inv = sInv[lr];
        const float* wr = fcw + (size_t)(c0 + lr) * 256 + seg * 64;
        unsigned short* dst = &sW[lr][seg * 64];
        for (int k = 0; k < 64; k += 4) {
            float4 f = *(const float4*)(wr + k);
            dst[k + 0] = f2bf(f.x * inv); dst[k + 1] = f2bf(f.y * inv);
            dst[k + 2] = f2bf(f.z * inv); dst[k + 3] = f2bf(f.w * inv);
        }
    }
    __syncthreads();
    const int lane = tid & 63, w = tid >> 6, q = lane >> 4, ln = lane & 15;
    f32x4 acc[2][4];
    for (int rk = 0; rk < 2; ++rk)
        for (int nb = 0; nb < 4; ++nb) {
            float bv = fcb[c0 + nb * 16 + ln];
            acc[rk][nb] = (f32x4){bv, bv, bv, bv};
        }
    // tiled-h read: region = t*TSLICE + w*8192; frag(rk,kb) at
    // (kb*4+q)*256 + rk*128 + ln*8 shorts
    const unsigned short* P = h2s + (size_t)rb * TSLICE + w * 8192 + q * 256 + ln * 8;
    for (int kb = 0; kb < 8; ++kb) {
        bf16x8 a0 = *(const bf16x8*)(P + kb * 1024);
        bf16x8 a1 = *(const bf16x8*)(P + kb * 1024 + 128);
        for (int nb = 0; nb < 4; ++nb) {
            bf16x8 b = *(const bf16x8*)&sW[nb * 16 + ln][kb * 32 + q * 8];
            acc[0][nb] = MFMA(a0, b, acc[0][nb]);
            acc[1][nb] = MFMA(a1, b, acc[1][nb]);
        }
    }
    for (int rk = 0; rk < 2; ++rk)
        for (int nb = 0; nb < 4; ++nb)
            for (int r = 0; r < 4; ++r) {
                int bb = 32 * w + rk * 16 + q * 4 + r;
                int o = c0 + nb * 16 + ln;
                out[((size_t)bb * Tt + rb) * 256 + o] = acc[rk][nb][r];
            }
}

extern "C" void kernel_launch(void* const* d_in, const int* in_sizes, int n_in,
                              void* d_out, int out_size, void* d_ws, size_t ws_size,
                              hipStream_t stream) {
    const float* x    = (const float*)d_in[0];
    const float* Wih1 = (const float*)d_in[1];
    const float* Whh1 = (const float*)d_in[2];
    const float* bih1 = (const float*)d_in[3];
    const float* bhh1 = (const float*)d_in[4];
    const float* Wih2 = (const float*)d_in[5];
    const float* Whh2 = (const float*)d_in[6];
    const float* bih2 = (const float*)d_in[7];
    const float* bhh2 = (const float*)d_in[8];
    const float* fcw  = (const float*)d_in[9];
    const float* fcb  = (const float*)d_in[10];

    char* ws = (char*)d_ws;
    unsigned short* xT  = (unsigned short*)ws;
    unsigned short* h1s = xT + (size_t)Tt * Bt * Vt;
    unsigned short* h2s = h1s + (size_t)Tt * Bt * Vt;

    fill_kernel<<<16384, 256, 0, stream>>>(h1s);  // h1s+h2s contiguous
    cvt_kernel<<<16384, 256, 0, stream>>>(x, xT);
    rec_kernel<<<64, 256, 0, stream>>>(Wih1, Whh1, bih1, bhh1,
                                       Wih2, Whh2, bih2, bhh2,
                                       xT, h1s, h2s);
    fc_kernel<<<4096, 256, 0, stream>>>(h2s, fcw, fcb, (float*)d_out);
}